// Round 1
// baseline (357.736 us; speedup 1.0000x reference)
//
#include <hip/hip_runtime.h>
#include <stdint.h>

#define BATCH 128
#define NN 512
#define BINS 100
#define WORDS 8   // 512 bits / 64
#define WPAD 9    // +1 u64 pad -> 2-way-max LDS bank aliasing (free)

// One block per graph (256 blocks). Phase 1: stream 1 MB graph from HBM with
// float4 loads, pack to LDS bitset via ballot. Phase 2: triangle count via
// AND+popcount, clustering coeff, LDS histogram. Writes hist[gb][100] to ws.
__global__ __launch_bounds__(1024) void k_cluster_hist(
    const float* __restrict__ adj1, const float* __restrict__ adj2,
    float* __restrict__ hist /* [2*BATCH][BINS] */)
{
    __shared__ unsigned long long bits[NN][WPAD];
    __shared__ int histI[BINS];

    const int gb = blockIdx.x;  // 0..255 ; 0..127 -> adj1, 128..255 -> adj2
    const float* __restrict__ g =
        (gb < BATCH ? adj1 : adj2) + (size_t)(gb & (BATCH - 1)) * NN * NN;

    const int tid  = threadIdx.x;
    const int lane = tid & 63;
    const int wave = tid >> 6;  // 0..15

    if (tid < BINS) histI[tid] = 0;

    // ---- Phase 1: pack. Each wave handles rows wave, wave+16, ...
    // Lane L loads float4 at cols seg*256 + 4L .. +3. Ballot on component q
    // produces the 64-bit word m = seg*4+q whose bit L corresponds to column
    // j = seg*256 + 4L + q. Mapping is consistent across rows, so AND/popcount
    // and degree are unaffected; neighbor column index is recovered in phase 2.
    #pragma unroll 2
    for (int r = wave; r < NN; r += 16) {
        const float* rowp = g + (size_t)r * NN;
        #pragma unroll
        for (int seg = 0; seg < 2; ++seg) {
            float4 v = *(const float4*)(rowp + seg * 256 + 4 * lane);
            unsigned long long m0 = __ballot(v.x != 0.0f);
            unsigned long long m1 = __ballot(v.y != 0.0f);
            unsigned long long m2 = __ballot(v.z != 0.0f);
            unsigned long long m3 = __ballot(v.w != 0.0f);
            if (lane == 0) {
                bits[r][seg * 4 + 0] = m0;
                bits[r][seg * 4 + 1] = m1;
                bits[r][seg * 4 + 2] = m2;
                bits[r][seg * 4 + 3] = m3;
            }
        }
    }
    __syncthreads();

    // ---- Phase 2: per row i: deg, tri2 = sum_{j in N(i)} |N(i) ∩ N(j)|.
    for (int r = wave; r < NN; r += 16) {
        unsigned long long row[WORDS];
        int deg = 0;
        #pragma unroll
        for (int w = 0; w < WORDS; ++w) {
            row[w] = bits[r][w];          // broadcast read (all lanes same addr)
            deg += __popcll(row[w]);
        }
        int acc = 0;
        #pragma unroll
        for (int m = 0; m < WORDS; ++m) {
            if ((row[m] >> lane) & 1ull) {
                // column index for (word m, bit lane) under the packed mapping
                int j = ((m >> 2) << 8) + 4 * lane + (m & 3);
                #pragma unroll
                for (int w = 0; w < WORDS; ++w)
                    acc += __popcll(row[w] & bits[j][w]);
            }
        }
        // wave-wide sum of acc (64 lanes)
        #pragma unroll
        for (int off = 32; off >= 1; off >>= 1)
            acc += __shfl_xor(acc, off, 64);

        if (lane == 0) {
            float tri2  = (float)acc;
            float degf  = (float)deg;
            float denom = degf * (degf - 1.0f);
            float c = denom > 0.0f ? tri2 / denom : 0.0f;  // exact: int/int in fp32
            int idx = (int)(c * 100.0f);                    // trunc, same as astype(int32)
            idx = idx < 0 ? 0 : (idx > BINS - 1 ? BINS - 1 : idx);
            atomicAdd(&histI[idx], 1);
        }
    }
    __syncthreads();

    if (tid < BINS) hist[(size_t)gb * BINS + tid] = (float)histI[tid];
}

// Pair-sum over the three 128x128 RBF kernel matrices (XX:+1, YY:+1, XY:-2).
__global__ __launch_bounds__(256) void k_mmd_partial(
    const float* __restrict__ hist, float* __restrict__ partials)
{
    const int total = 3 * BATCH * BATCH;  // 49152
    int tid = blockIdx.x * blockDim.x + threadIdx.x;
    int nth = gridDim.x * blockDim.x;
    float local = 0.0f;
    for (int p = tid; p < total; p += nth) {
        int t   = p / (BATCH * BATCH);
        int rem = p - t * (BATCH * BATCH);
        int i = rem >> 7;
        int j = rem & 127;
        const float* x;
        const float* y;
        float w;
        if (t == 0)      { x = hist + (size_t)i * BINS;           y = hist + (size_t)j * BINS;           w =  1.0f; }
        else if (t == 1) { x = hist + (size_t)(BATCH + i) * BINS; y = hist + (size_t)(BATCH + j) * BINS; w =  1.0f; }
        else             { x = hist + (size_t)i * BINS;           y = hist + (size_t)(BATCH + j) * BINS; w = -2.0f; }
        float sq = 0.0f;
        #pragma unroll 4
        for (int k = 0; k < BINS; ++k) {
            float d = x[k] - y[k];
            sq += d * d;
        }
        local += w * expf(-0.5f * sq);  // sigma = 1 -> 1/(2 sigma^2) = 0.5
    }
    __shared__ float red[256];
    red[threadIdx.x] = local;
    __syncthreads();
    for (int s = 128; s >= 1; s >>= 1) {
        if (threadIdx.x < s) red[threadIdx.x] += red[threadIdx.x + s];
        __syncthreads();
    }
    if (threadIdx.x == 0) partials[blockIdx.x] = red[0];
}

__global__ __launch_bounds__(64) void k_mmd_final(
    const float* __restrict__ partials, float* __restrict__ out, int nparts)
{
    int lane = threadIdx.x;
    float v = 0.0f;
    for (int p = lane; p < nparts; p += 64) v += partials[p];
    #pragma unroll
    for (int off = 32; off >= 1; off >>= 1) v += __shfl_xor(v, off, 64);
    if (lane == 0) out[0] = v * (1.0f / (float)(BATCH * BATCH));
}

extern "C" void kernel_launch(void* const* d_in, const int* in_sizes, int n_in,
                              void* d_out, int out_size, void* d_ws, size_t ws_size,
                              hipStream_t stream) {
    const float* a1 = (const float*)d_in[0];
    const float* a2 = (const float*)d_in[1];
    float* hist     = (float*)d_ws;                                   // 2*128*100 floats
    float* partials = (float*)((char*)d_ws + 2 * BATCH * BINS * sizeof(float)); // 96 floats
    float* out      = (float*)d_out;

    hipLaunchKernelGGL(k_cluster_hist, dim3(2 * BATCH), dim3(1024), 0, stream,
                       a1, a2, hist);
    hipLaunchKernelGGL(k_mmd_partial, dim3(96), dim3(256), 0, stream,
                       hist, partials);
    hipLaunchKernelGGL(k_mmd_final, dim3(1), dim3(64), 0, stream,
                       partials, out, 96);
}

// Round 2
// 282.838 us; speedup vs baseline: 1.2648x; 1.2648x over previous
//
#include <hip/hip_runtime.h>
#include <stdint.h>

#define BATCH 128
#define NN 512
#define BINS 100
#define WORDS 8    // 512 bits / 64
#define WPAD 9     // +1 u64 pad -> benign LDS bank aliasing
#define ECAP 6144  // upper-tri edge capacity; expected ~2675, >25 sigma margin

// One block per graph (256 blocks = 1/CU).
// Phase 1: stream 1 MB graph from HBM with float4 loads, pack to LDS bitset
//          via ballot (bit->column mapping permuted but consistent; true
//          column recovered as j = (m>>2)*256 + 4*lane + (m&3)).
// Phase 2a: compact upper-triangle edge list in LDS via ctz bit-extraction.
// Phase 2b: edge-parallel triangle counting — all 64 lanes do useful
//           AND+popcount work (fixes the divergence that made R1 issue-bound).
// Phase 2c: per-row clustering coeff + LDS histogram.
__global__ __launch_bounds__(1024) void k_cluster_hist(
    const float* __restrict__ adj1, const float* __restrict__ adj2,
    float* __restrict__ hist /* [2*BATCH][BINS] */)
{
    __shared__ unsigned long long bits[NN][WPAD];   // 36,864 B
    __shared__ unsigned int edges[ECAP];            // 24,576 B  (r<<10 | j)
    __shared__ int tri2[NN];                        //  2,048 B
    __shared__ int histI[BINS];
    __shared__ int ecnt;

    const int gb = blockIdx.x;  // 0..255 ; 0..127 -> adj1, 128..255 -> adj2
    const float* __restrict__ g =
        (gb < BATCH ? adj1 : adj2) + (size_t)(gb & (BATCH - 1)) * NN * NN;

    const int tid  = threadIdx.x;
    const int lane = tid & 63;
    const int wave = tid >> 6;  // 0..15

    if (tid < BINS) histI[tid] = 0;
    if (tid < NN)   tri2[tid]  = 0;
    if (tid == 0)   ecnt = 0;

    // ---- Phase 1: pack 512x512 fp32 -> 512x512-bit LDS bitset.
    #pragma unroll 2
    for (int r = wave; r < NN; r += 16) {
        const float* rowp = g + (size_t)r * NN;
        #pragma unroll
        for (int seg = 0; seg < 2; ++seg) {
            float4 v = *(const float4*)(rowp + seg * 256 + 4 * lane);
            unsigned long long m0 = __ballot(v.x != 0.0f);
            unsigned long long m1 = __ballot(v.y != 0.0f);
            unsigned long long m2 = __ballot(v.z != 0.0f);
            unsigned long long m3 = __ballot(v.w != 0.0f);
            if (lane == 0) {
                bits[r][seg * 4 + 0] = m0;
                bits[r][seg * 4 + 1] = m1;
                bits[r][seg * 4 + 2] = m2;
                bits[r][seg * 4 + 3] = m3;
            }
        }
    }
    __syncthreads();

    // ---- Phase 2a: build upper-triangle edge list (j > r).
    // 4096 (row, word) pairs over 1024 threads.
    for (int p = tid; p < NN * WORDS; p += 1024) {
        int r = p >> 3;
        int m = p & 7;
        unsigned long long w = bits[r][m];
        while (w) {
            int L = __builtin_ctzll(w);
            w &= w - 1;
            int j = ((m >> 2) << 8) + 4 * L + (m & 3);  // true column index
            if (j > r) {
                int slot = atomicAdd(&ecnt, 1);
                if (slot < ECAP) edges[slot] = ((unsigned)r << 10) | (unsigned)j;
            }
        }
    }
    __syncthreads();

    // ---- Phase 2b: edge-parallel intersection counts.
    const int ne = ecnt < ECAP ? ecnt : ECAP;
    for (int e = tid; e < ne; e += 1024) {
        unsigned ed = edges[e];
        int i = ed >> 10;
        int j = ed & 1023;
        int acc = 0;
        #pragma unroll
        for (int w = 0; w < WORDS; ++w)
            acc += __popcll(bits[i][w] & bits[j][w]);
        atomicAdd(&tri2[i], acc);
        atomicAdd(&tri2[j], acc);
    }
    __syncthreads();

    // ---- Phase 2c: clustering coeff + histogram.
    if (tid < NN) {
        int deg = 0;
        #pragma unroll
        for (int w = 0; w < WORDS; ++w) deg += __popcll(bits[tid][w]);
        float t2    = (float)tri2[tid];
        float degf  = (float)deg;
        float denom = degf * (degf - 1.0f);
        float c = denom > 0.0f ? t2 / denom : 0.0f;  // exact int/int in fp32
        int idx = (int)(c * 100.0f);                  // trunc == astype(int32)
        idx = idx < 0 ? 0 : (idx > BINS - 1 ? BINS - 1 : idx);
        atomicAdd(&histI[idx], 1);
    }
    __syncthreads();

    if (tid < BINS) hist[(size_t)gb * BINS + tid] = (float)histI[tid];
}

// RBF pair kernels: one pair per thread, float4 loads. 192*256 = 49152 = 3*128*128.
__global__ __launch_bounds__(256) void k_mmd_partial(
    const float* __restrict__ hist, float* __restrict__ partials)
{
    int p = blockIdx.x * 256 + threadIdx.x;
    int t   = p >> 14;          // 0:XX 1:YY 2:XY
    int rem = p & 16383;
    int i = rem >> 7;
    int j = rem & 127;
    const float4* x4;
    const float4* y4;
    float w;
    if (t == 0)      { x4 = (const float4*)(hist + (size_t)i * BINS);           y4 = (const float4*)(hist + (size_t)j * BINS);           w =  1.0f; }
    else if (t == 1) { x4 = (const float4*)(hist + (size_t)(BATCH + i) * BINS); y4 = (const float4*)(hist + (size_t)(BATCH + j) * BINS); w =  1.0f; }
    else             { x4 = (const float4*)(hist + (size_t)i * BINS);           y4 = (const float4*)(hist + (size_t)(BATCH + j) * BINS); w = -2.0f; }
    float sq = 0.0f;
    #pragma unroll
    for (int k = 0; k < BINS / 4; ++k) {  // 100 floats = 25 float4 (rows 400B-aligned)
        float4 a = x4[k];
        float4 b = y4[k];
        float d0 = a.x - b.x, d1 = a.y - b.y, d2 = a.z - b.z, d3 = a.w - b.w;
        sq += d0 * d0 + d1 * d1 + d2 * d2 + d3 * d3;
    }
    float local = w * expf(-0.5f * sq);  // sigma=1 -> 1/(2 sigma^2) = 0.5

    __shared__ float red[256];
    red[threadIdx.x] = local;
    __syncthreads();
    for (int s = 128; s >= 1; s >>= 1) {
        if (threadIdx.x < s) red[threadIdx.x] += red[threadIdx.x + s];
        __syncthreads();
    }
    if (threadIdx.x == 0) partials[blockIdx.x] = red[0];
}

__global__ __launch_bounds__(64) void k_mmd_final(
    const float* __restrict__ partials, float* __restrict__ out, int nparts)
{
    int lane = threadIdx.x;
    float v = 0.0f;
    for (int p = lane; p < nparts; p += 64) v += partials[p];
    #pragma unroll
    for (int off = 32; off >= 1; off >>= 1) v += __shfl_xor(v, off, 64);
    if (lane == 0) out[0] = v * (1.0f / (float)(BATCH * BATCH));
}

extern "C" void kernel_launch(void* const* d_in, const int* in_sizes, int n_in,
                              void* d_out, int out_size, void* d_ws, size_t ws_size,
                              hipStream_t stream) {
    const float* a1 = (const float*)d_in[0];
    const float* a2 = (const float*)d_in[1];
    float* hist     = (float*)d_ws;                                   // 2*128*100 floats
    float* partials = (float*)((char*)d_ws + 2 * BATCH * BINS * sizeof(float)); // 192 floats
    float* out      = (float*)d_out;

    hipLaunchKernelGGL(k_cluster_hist, dim3(2 * BATCH), dim3(1024), 0, stream,
                       a1, a2, hist);
    hipLaunchKernelGGL(k_mmd_partial, dim3(192), dim3(256), 0, stream,
                       hist, partials);
    hipLaunchKernelGGL(k_mmd_final, dim3(1), dim3(64), 0, stream,
                       partials, out, 192);
}